// Round 4
// baseline (4509.930 us; speedup 1.0000x reference)
//
#include <hip/hip_runtime.h>

// ECGLSTM: B=256, T=5000, input_size=1, H=64, fused FC(64->128)+ReLU.
// R4 = R3 with the exp intrinsic fixed (__builtin_amdgcn_exp2f, native
// base-2 v_exp_f32). ONE WAVE per batch element (64-thread blocks, grid=256).
// Lane u owns hidden unit u and computes ALL FOUR gates for it (W_hh rows
// u, 64+u, 128+u, 192+u live in 256 VGPRs). All cross-lane exchange (h
// broadcast) is intra-wave through a wave-private LDS buffer -> ordered by
// lgkmcnt only, ZERO barriers in the recurrence. Dot products issue as
// v_pk_fma_f32 (packed 2xfp32) -> 128 pk-FMA = 256 issue cycles/step.
// x staged in a register (64 steps/chunk, prefetched 1 chunk ahead),
// broadcast via one readlane per step.

#define LSTM_H 64
#define LSTM_T 5000
#define LSTM_B 256

typedef float v2f __attribute__((ext_vector_type(2)));

__device__ __forceinline__ v2f pk_fma(v2f a, v2f b, v2f c) {
    v2f d;
    asm("v_pk_fma_f32 %0, %1, %2, %3" : "=v"(d) : "v"(a), "v"(b), "v"(c));
    return d;
}

__device__ __forceinline__ float rl(float v, int lane) {
    return __int_as_float(__builtin_amdgcn_readlane(__float_as_int(v), lane));
}

#define LOG2E 1.44269504088896340736f

__device__ __forceinline__ float fast_sig(float x) {
    // sigmoid(x) = 1 / (1 + 2^(-x*log2e))
    float e = __builtin_amdgcn_exp2f(-LOG2E * x);
    return __builtin_amdgcn_rcpf(1.0f + e);
}
__device__ __forceinline__ float fast_tanh(float x) {
    // tanh(x) = 1 - 2/(2^(2*log2e*x) + 1)
    float e = __builtin_amdgcn_exp2f((2.0f * LOG2E) * x);
    return 1.0f - 2.0f * __builtin_amdgcn_rcpf(e + 1.0f);
}

__global__ __launch_bounds__(64, 1) void ECGLSTM_lstm_fused(
    const float* __restrict__ x,      // [B, T]
    const float* __restrict__ W_ih,   // [4H, 1]
    const float* __restrict__ W_hh,   // [4H, H]
    const float* __restrict__ b_ih,   // [4H]
    const float* __restrict__ b_hh,   // [4H]
    const float* __restrict__ W_fc,   // [128, H]
    const float* __restrict__ b_fc,   // [128]
    float* __restrict__ out)          // [B, 128]
{
    const int u = threadIdx.x;        // hidden unit 0..63
    const int b = blockIdx.x;         // batch element

    __shared__ float h_lds[LSTM_H];   // wave-private h broadcast buffer

    // Four W_hh rows for unit u -> 128 v2f registers (256 VGPRs)
    v2f w0[32], w1[32], w2[32], w3[32];
    {
        const float4* r0 = reinterpret_cast<const float4*>(W_hh + (0 * LSTM_H + u) * LSTM_H);
        const float4* r1 = reinterpret_cast<const float4*>(W_hh + (1 * LSTM_H + u) * LSTM_H);
        const float4* r2 = reinterpret_cast<const float4*>(W_hh + (2 * LSTM_H + u) * LSTM_H);
        const float4* r3 = reinterpret_cast<const float4*>(W_hh + (3 * LSTM_H + u) * LSTM_H);
        #pragma unroll
        for (int i = 0; i < 16; ++i) {
            float4 v;
            v = r0[i]; w0[2*i] = v2f{v.x, v.y}; w0[2*i+1] = v2f{v.z, v.w};
            v = r1[i]; w1[2*i] = v2f{v.x, v.y}; w1[2*i+1] = v2f{v.z, v.w};
            v = r2[i]; w2[2*i] = v2f{v.x, v.y}; w2[2*i+1] = v2f{v.z, v.w};
            v = r3[i]; w3[2*i] = v2f{v.x, v.y}; w3[2*i+1] = v2f{v.z, v.w};
        }
    }
    const float wih0 = W_ih[0 * LSTM_H + u];
    const float wih1 = W_ih[1 * LSTM_H + u];
    const float wih2 = W_ih[2 * LSTM_H + u];
    const float wih3 = W_ih[3 * LSTM_H + u];
    const float bia0 = b_ih[0 * LSTM_H + u] + b_hh[0 * LSTM_H + u];
    const float bia1 = b_ih[1 * LSTM_H + u] + b_hh[1 * LSTM_H + u];
    const float bia2 = b_ih[2 * LSTM_H + u] + b_hh[2 * LSTM_H + u];
    const float bia3 = b_ih[3 * LSTM_H + u] + b_hh[3 * LSTM_H + u];

    float c = 0.0f;
    h_lds[u] = 0.0f;                  // in-wave: ordered vs later ds_reads by lgkmcnt

    const float* xb = x + b * LSTM_T;
    float xcur = xb[u];               // chunk 0 (64 timesteps in one VGPR)

    for (int base = 0; base < LSTM_T; base += 64) {
        const int nt = (LSTM_T - base < 64) ? (LSTM_T - base) : 64;
        // prefetch next chunk of x (consumed 64 steps from now)
        const int nb = base + 64;
        float xnext = 0.0f;
        if (nb < LSTM_T && u < LSTM_T - nb) xnext = xb[nb + u];

        for (int tt = 0; tt < nt; ++tt) {
            const float xv = rl(xcur, tt);   // 1 readlane/step

            v2f a0 = {0.f, 0.f}, c0 = {0.f, 0.f};
            v2f a1 = {0.f, 0.f}, c1 = {0.f, 0.f};
            v2f a2 = {0.f, 0.f}, c2 = {0.f, 0.f};
            v2f a3 = {0.f, 0.f}, c3 = {0.f, 0.f};
            const float4* h4 = reinterpret_cast<const float4*>(h_lds);
            #pragma unroll
            for (int i = 0; i < 16; ++i) {
                float4 hv = h4[i];           // ds_read_b128 broadcast
                v2f hlo = {hv.x, hv.y};
                v2f hhi = {hv.z, hv.w};
                a0 = pk_fma(hlo, w0[2*i], a0);  c0 = pk_fma(hhi, w0[2*i+1], c0);
                a1 = pk_fma(hlo, w1[2*i], a1);  c1 = pk_fma(hhi, w1[2*i+1], c1);
                a2 = pk_fma(hlo, w2[2*i], a2);  c2 = pk_fma(hhi, w2[2*i+1], c2);
                a3 = pk_fma(hlo, w3[2*i], a3);  c3 = pk_fma(hhi, w3[2*i+1], c3);
            }
            float g0 = fmaf(xv, wih0, bia0) + ((a0.x + a0.y) + (c0.x + c0.y));
            float g1 = fmaf(xv, wih1, bia1) + ((a1.x + a1.y) + (c1.x + c1.y));
            float g2 = fmaf(xv, wih2, bia2) + ((a2.x + a2.y) + (c2.x + c2.y));
            float g3 = fmaf(xv, wih3, bia3) + ((a3.x + a3.y) + (c3.x + c3.y));

            const float ig = fast_sig(g0);
            const float fg = fast_sig(g1);
            const float gg = fast_tanh(g2);
            const float og = fast_sig(g3);
            c = fmaf(fg, c, ig * gg);
            const float h = og * fast_tanh(c);
            h_lds[u] = h;                // next iter's ds_read waits on lgkmcnt
        }
        xcur = xnext;
    }

    // Epilogue: FC(64->128)+ReLU. Lane u computes output rows u and 64+u.
    {
        const float4* h4  = reinterpret_cast<const float4*>(h_lds);
        const float4* wfa = reinterpret_cast<const float4*>(W_fc + u * LSTM_H);
        const float4* wfb = reinterpret_cast<const float4*>(W_fc + (64 + u) * LSTM_H);
        float s0 = b_fc[u];
        float s1 = b_fc[64 + u];
        #pragma unroll
        for (int i = 0; i < 16; ++i) {
            float4 hv = h4[i];
            float4 wa = wfa[i];
            float4 wb = wfb[i];
            s0 = fmaf(hv.x, wa.x, s0); s0 = fmaf(hv.y, wa.y, s0);
            s0 = fmaf(hv.z, wa.z, s0); s0 = fmaf(hv.w, wa.w, s0);
            s1 = fmaf(hv.x, wb.x, s1); s1 = fmaf(hv.y, wb.y, s1);
            s1 = fmaf(hv.z, wb.z, s1); s1 = fmaf(hv.w, wb.w, s1);
        }
        out[b * 128 + u]      = fmaxf(s0, 0.0f);
        out[b * 128 + 64 + u] = fmaxf(s1, 0.0f);
    }
}

extern "C" void kernel_launch(void* const* d_in, const int* in_sizes, int n_in,
                              void* d_out, int out_size, void* d_ws, size_t ws_size,
                              hipStream_t stream) {
    const float* x    = (const float*)d_in[0];
    const float* W_ih = (const float*)d_in[1];
    const float* W_hh = (const float*)d_in[2];
    const float* b_ih = (const float*)d_in[3];
    const float* b_hh = (const float*)d_in[4];
    const float* W_fc = (const float*)d_in[5];
    const float* b_fc = (const float*)d_in[6];
    float* out = (float*)d_out;

    ECGLSTM_lstm_fused<<<LSTM_B, 64, 0, stream>>>(
        x, W_ih, W_hh, b_ih, b_hh, W_fc, b_fc, out);
}

// Round 5
// 2080.319 us; speedup vs baseline: 2.1679x; 2.1679x over previous
//
#include <hip/hip_runtime.h>

// ECGLSTM: B=256, T=5000, input_size=1, H=64, fused FC(64->128)+ReLU.
// R5: block=256 (4 waves) per batch element, thread tid owns gate tid
// (32 v2f = 64 VGPRs of W_hh row -> NO spills, unlike R4's 256-VGPR blowup).
// - c/h update REPLICATED in all 4 waves: each wave's 64 lanes write the
//   full h vector, so every wave reads only its OWN h writes (lgkmcnt-
//   ordered) -> h needs no barrier protection.
// - ONE barrier/step (gates exchange only), double-buffered gates+h kill
//   the WAR hazards the second barrier used to cover.
// - v_pk_fma_f32 with tied accumulator: 32 packed FMA = 64 issue cyc/step.
// - x row staged to LDS once (20 KB): no global loads in the loop, so the
//   barrier's vmcnt(0) drain is free.
// - Activation arithmetic bitwise-identical to R1 (absmax 3.8e-6 there).

#define LSTM_H 64
#define LSTM_T 5000
#define LSTM_B 256

typedef float v2f __attribute__((ext_vector_type(2)));

__device__ __forceinline__ void pk_fma_acc(v2f& acc, v2f a, v2f b) {
    // acc = a*b + acc, accumulate in place (tied operand -> no v_mov)
    asm("v_pk_fma_f32 %0, %1, %2, %0" : "+v"(acc) : "v"(a), "v"(b));
}

__device__ __forceinline__ float fast_rcp(float v) {
    return __builtin_amdgcn_rcpf(v);
}

__global__ __launch_bounds__(256) void ECGLSTM_lstm_fused(
    const float* __restrict__ x,      // [B, T]
    const float* __restrict__ W_ih,   // [4H, 1]
    const float* __restrict__ W_hh,   // [4H, H]
    const float* __restrict__ b_ih,   // [4H]
    const float* __restrict__ b_hh,   // [4H]
    const float* __restrict__ W_fc,   // [128, H]
    const float* __restrict__ b_fc,   // [128]
    float* __restrict__ out)          // [B, 128]
{
    const int tid  = threadIdx.x;     // gate index 0..255
    const int lane = tid & 63;        // hidden unit this thread updates
    const int b    = blockIdx.x;

    __shared__ float xch[LSTM_T];             // whole x row, staged once
    __shared__ float hbuf[2][LSTM_H];         // double-buffered h
    __shared__ float gbuf[2][4 * LSTM_H];     // double-buffered gates

    // Stage x (coalesced, once)
    const float* xb = x + b * LSTM_T;
    for (int i = tid; i < LSTM_T; i += 256) xch[i] = xb[i];

    // W_hh row `tid` -> 32 v2f (64 VGPRs)
    v2f w[LSTM_H / 2];
    {
        const float4* wrow = reinterpret_cast<const float4*>(W_hh + tid * LSTM_H);
        #pragma unroll
        for (int i = 0; i < LSTM_H / 4; ++i) {
            float4 v = wrow[i];
            w[2 * i]     = v2f{v.x, v.y};
            w[2 * i + 1] = v2f{v.z, v.w};
        }
    }
    const float wih  = W_ih[tid];
    const float bias = b_ih[tid] + b_hh[tid];
    const bool  is_tanh = ((tid >> 6) == 2);   // wave-uniform branch

    float c = 0.0f;                   // replicated: lane j of every wave has c[j]
    hbuf[0][lane] = 0.0f;             // every wave writes full h0 (identical values)
    __syncthreads();                  // x staged + h0 visible

    // One LSTM step at parity P: read hbuf[P]/gbuf[P], write hbuf[1-P].
    #define LSTM_STEP(t, P)                                                    \
    {                                                                          \
        const float xv = xch[(t)];                      /* broadcast b32 */    \
        v2f A = {0.f, 0.f}, C = {0.f, 0.f};                                    \
        const float4* h4 = reinterpret_cast<const float4*>(hbuf[(P)]);         \
        _Pragma("unroll")                                                      \
        for (int i = 0; i < LSTM_H / 4; ++i) {                                 \
            float4 hv = h4[i];                          /* b128 broadcast */   \
            pk_fma_acc(A, v2f{hv.x, hv.y}, w[2 * i]);                          \
            pk_fma_acc(C, v2f{hv.z, hv.w}, w[2 * i + 1]);                      \
        }                                                                      \
        float g = fmaf(xv, wih, bias) + ((A.x + A.y) + (C.x + C.y));           \
        float act;                                                             \
        if (is_tanh) {                                                         \
            float e = __expf(2.0f * g);                                        \
            act = 1.0f - 2.0f * fast_rcp(e + 1.0f);                            \
        } else {                                                               \
            float e = __expf(-g);                                              \
            act = fast_rcp(1.0f + e);                                          \
        }                                                                      \
        gbuf[(P)][tid] = act;                                                  \
        __syncthreads();                                /* the ONE barrier */  \
        const float ig = gbuf[(P)][lane];                                      \
        const float fg = gbuf[(P)][LSTM_H + lane];                             \
        const float gg = gbuf[(P)][2 * LSTM_H + lane];                         \
        const float og = gbuf[(P)][3 * LSTM_H + lane];                         \
        c = fmaf(fg, c, ig * gg);                                              \
        float e2 = __expf(2.0f * c);                                           \
        float th = 1.0f - 2.0f * fast_rcp(e2 + 1.0f);                          \
        hbuf[1 - (P)][lane] = og * th;                  /* all waves, same */  \
    }

    for (int t = 0; t < LSTM_T; t += 2) {
        LSTM_STEP(t, 0);
        LSTM_STEP(t + 1, 1);
    }
    #undef LSTM_STEP

    // Final h is in hbuf[0] (T even); each wave wrote it itself -> no barrier.
    // FC(64->128)+ReLU: threads 0..127 compute one output row each.
    if (tid < 128) {
        float s = b_fc[tid];
        const float4* wf = reinterpret_cast<const float4*>(W_fc + tid * LSTM_H);
        const float4* h4 = reinterpret_cast<const float4*>(hbuf[0]);
        #pragma unroll
        for (int i = 0; i < LSTM_H / 4; ++i) {
            float4 wv = wf[i];
            float4 hv = h4[i];
            s = fmaf(hv.x, wv.x, s);
            s = fmaf(hv.y, wv.y, s);
            s = fmaf(hv.z, wv.z, s);
            s = fmaf(hv.w, wv.w, s);
        }
        out[b * 128 + tid] = fmaxf(s, 0.0f);
    }
}

extern "C" void kernel_launch(void* const* d_in, const int* in_sizes, int n_in,
                              void* d_out, int out_size, void* d_ws, size_t ws_size,
                              hipStream_t stream) {
    const float* x    = (const float*)d_in[0];
    const float* W_ih = (const float*)d_in[1];
    const float* W_hh = (const float*)d_in[2];
    const float* b_ih = (const float*)d_in[3];
    const float* b_hh = (const float*)d_in[4];
    const float* W_fc = (const float*)d_in[5];
    const float* b_fc = (const float*)d_in[6];
    float* out = (float*)d_out;

    ECGLSTM_lstm_fused<<<LSTM_B, 256, 0, stream>>>(
        x, W_ih, W_hh, b_ih, b_hh, W_fc, b_fc, out);
}